// Round 4
// baseline (175.131 us; speedup 1.0000x reference)
//
#include <hip/hip_runtime.h>
#include <stdint.h>

// ---------------------------------------------------------------------------
// MaskedAttentionHead: B=4, S=2048, d_model=1024, d_k=64
// R12: R11 post-mortem — persistent 1-blk/CU pipeline ALSO hit the ~2.2 TB/s
// consumed-read wall (44.7us; occ 8.5%, structure verified by VGPR 132 /
// LDS 148K). Wall now reproduced across: lane-pattern loads, contiguous
// 8-wave deep (R8 40.2), 16-wave shallow (R9 42.8, VGPR collapse 52),
// 4-wave deep persistent (R11 44.7). Untested cell: MANY waves x DEEP
// bursts. R9 meant to test it but bounds(256,4) cap=128 killed the 64-reg
// burst. R12 = R9 structure (no W LDS, no mid-loop barriers, 33 KB LDS)
// with bounds(256,3): VGPR cap 168 keeps the 16-deep burst, 3 blk/CU =
// 12 waves, ~190 KB reads in flight per CU, blocks independent (no lockstep
// idle). Falsification: VGPR>=120 and proj>=40us => wall is hard, pivot to
// attn. attn/wcvt byte-identical to R11 for attribution.
// ---------------------------------------------------------------------------

typedef __bf16 bf16x8 __attribute__((ext_vector_type(8)));
typedef float  f32x4  __attribute__((ext_vector_type(4)));
typedef unsigned short u16;
typedef unsigned int   u32;

__device__ __forceinline__ u16 f2bf(float f) {
  u32 u = __float_as_uint(f);
  u += 0x7fffu + ((u >> 16) & 1u);          // round-to-nearest-even
  return (u16)(u >> 16);
}

// --------------------------- W fp32 -> bf16 --------------------------------
__global__ __launch_bounds__(256) void wcvt_kernel(
    const float* __restrict__ Wq, const float* __restrict__ Wk,
    const float* __restrict__ Wv, u16* __restrict__ Wbf) {
  int i = (blockIdx.x * 256 + threadIdx.x) * 4;   // 3*64*1024 = 196608 total
  const float* src = (i < 65536) ? Wq : (i < 131072) ? Wk : Wv;
  int off = i & 65535;
  float4 f = *(const float4*)(src + off);
  *(ushort4*)(Wbf + i) = make_ushort4(f2bf(f.x), f2bf(f.y), f2bf(f.z), f2bf(f.w));
}

// --------------------------- projections -----------------------------------
// grid 1536 (which = bx%3, 512 row-blocks), block 256 (4 waves), 3 blocks/CU
// (VGPR-bound; LDS 33 KB would allow 4). Block owns 16 rows. Wave w bursts
// rows w*4..w*4+3 as 16 contiguous 1-KB float4 loads into 64 named VGPRs
// (bounds(256,3) cap=168 keeps them live), cvt -> padded LDS. Compute: wave's
// 64-wide k-slice per quarter qq; A-frag from LDS (2-way = free), W B-frag
// straight from global (L2-resident). No barriers inside the K-loop.
// Combine 4 k-partials via os overlay on xl.
__global__ __launch_bounds__(256, 3) void proj_kernel(
    const float* __restrict__ q, const float* __restrict__ k,
    const float* __restrict__ v, const u16* __restrict__ Wbf,
    u16* __restrict__ qh, u16* __restrict__ kh, u16* __restrict__ vhT) {
  __shared__ u16 xl[16][1032];   // X tile bf16; stride 2064 B -> 2-way (free)
  const int tid = threadIdx.x;
  const int lane = tid & 63, w = tid >> 6;
  const int c16 = lane & 15, quad = lane >> 4;
  const int which = blockIdx.x % 3;
  const int r0 = (blockIdx.x / 3) * 16;
  const float* X = (which == 0) ? q : (which == 1) ? k : v;
  const u16* wsrc = Wbf + which * 65536;

  // ---- X burst: 16 contiguous 1-KB float4 loads (wave's 4 rows) ----
  const float* xgw = X + (size_t)(r0 + w * 4) * 1024 + lane * 4;
  float4 ar[16];
#pragma unroll
  for (int i = 0; i < 16; i++) ar[i] = *(const float4*)(xgw + i * 256);

  // ---- X cvt -> LDS ----
#pragma unroll
  for (int i = 0; i < 16; i++) {
    ushort4 pk = make_ushort4(f2bf(ar[i].x), f2bf(ar[i].y),
                              f2bf(ar[i].z), f2bf(ar[i].w));
    *(ushort4*)&xl[w * 4 + (i >> 2)][(i & 3) * 256 + lane * 4] = pk;
  }
  __syncthreads();

  f32x4 acc[4];
#pragma unroll
  for (int nt = 0; nt < 4; nt++)
#pragma unroll
    for (int j = 0; j < 4; j++) acc[nt][j] = 0.0f;

  // W row base for this lane's B-frags: row = nt*16 + c16, col = qq*256 + kin
  const u16* wr = wsrc + (size_t)c16 * 1024;

#pragma unroll
  for (int qq = 0; qq < 4; qq++) {
#pragma unroll
    for (int ks = 0; ks < 2; ks++) {
      const int kin = w * 64 + ks * 32 + quad * 8;       // col within quarter
      bf16x8 af = *(const bf16x8*)&xl[c16][qq * 256 + kin];
#pragma unroll
      for (int nt = 0; nt < 4; nt++) {
        bf16x8 wf = *(const bf16x8*)(wr + (size_t)nt * 16384 + qq * 256 + kin);
        acc[nt] = __builtin_amdgcn_mfma_f32_16x16x32_bf16(af, wf, acc[nt], 0, 0, 0);
      }
    }
  }

  // ---- combine 4 k-partials via os overlay on xl (xl dead) ----
  __syncthreads();
  float* osp = (float*)&xl[0][0];            // os[w][16][64] = 16 KB
#pragma unroll
  for (int nt = 0; nt < 4; nt++)
#pragma unroll
    for (int rr = 0; rr < 4; rr++)
      osp[((size_t)w * 16 + quad * 4 + rr) * 64 + nt * 16 + c16] = acc[nt][rr];
  __syncthreads();

  if (which == 2) {
    const int col = tid >> 2, s4 = (tid & 3) * 4;
    float s[4];
#pragma unroll
    for (int rr = 0; rr < 4; rr++)
      s[rr] = osp[(0 * 16 + s4 + rr) * 64 + col] + osp[(1 * 16 + s4 + rr) * 64 + col] +
              osp[(2 * 16 + s4 + rr) * 64 + col] + osp[(3 * 16 + s4 + rr) * 64 + col];
    const int bb = r0 >> 11, s0 = (r0 & 2047) + s4;
    ushort4 pk = make_ushort4(f2bf(s[0]), f2bf(s[1]), f2bf(s[2]), f2bf(s[3]));
    *(ushort4*)(vhT + ((size_t)bb * 64 + col) * 2048 + s0) = pk;
  } else {
    u16* out = (which == 0) ? qh : kh;
    const int row = tid >> 4, c4 = (tid & 15) * 4;
    float s[4];
#pragma unroll
    for (int j = 0; j < 4; j++)
      s[j] = osp[(0 * 16 + row) * 64 + c4 + j] + osp[(1 * 16 + row) * 64 + c4 + j] +
             osp[(2 * 16 + row) * 64 + c4 + j] + osp[(3 * 16 + row) * 64 + c4 + j];
    ushort4 pk = make_ushort4(f2bf(s[0]), f2bf(s[1]), f2bf(s[2]), f2bf(s[3]));
    *(ushort4*)(out + (size_t)(r0 + row) * 64 + c4) = pk;
  }
}

// --------------------------- flash attention --------------------------------
// grid (128,4), block 512 (8 waves, kv-split 8). Transposed math:
//   S^T[kv][q] = K Q^T  (A=K-frag, B=Q-frag, both natural row-major)
//   O^T[d][q]  = V^T P^T (A=vhT-frag, B=P-frag from packed LDS)
// Mask scale is per-column q = c16 -> one scalar/lane. No kv-loop barriers.
__global__ __launch_bounds__(512, 4) void attn_kernel(
    const u16* __restrict__ qh, const u16* __restrict__ kh,
    const u16* __restrict__ vhT, const float* __restrict__ m,
    float* __restrict__ y) {
  __shared__ float Os[8][64][17];    // [w][d][q] +1 pad        34.8 KB
  __shared__ float Ls[8][16];
  __shared__ u16  Pl[8][16][68];     // [w][q][kv] +4 pad       17.4 KB
  const int tid = threadIdx.x;
  const int lane = tid & 63, w = tid >> 6;
  const int c16 = lane & 15, quad = lane >> 4;
  const int b = blockIdx.y;
  const int q0 = blockIdx.x * 16;

  // Q B-frags (n=q=c16, k=d contiguous), persistent
  bf16x8 qf[2];
  {
    const u16* qp = qh + (size_t)(b * 2048 + q0 + c16) * 64 + quad * 8;
    qf[0] = *(const bf16x8*)qp;
    qf[1] = *(const bf16x8*)(qp + 32);
  }
  const float fscale = 0.125f * m[b * 2048 + q0 + c16];

  f32x4 oacc[4];
#pragma unroll
  for (int nt = 0; nt < 4; nt++)
#pragma unroll
    for (int j = 0; j < 4; j++) oacc[nt][j] = 0.0f;
  float lsum = 0.0f;

  const u16* kb = kh + (size_t)b * 131072;
  const u16* vb = vhT + (size_t)b * 131072;

  for (int c = 0; c < 4; c++) {
    const int kv0 = w * 64 + c * 512;
    // ---- S^T = K Q^T ----
    f32x4 sacc[4];
#pragma unroll
    for (int nt = 0; nt < 4; nt++)
#pragma unroll
      for (int j = 0; j < 4; j++) sacc[nt][j] = 0.0f;
#pragma unroll
    for (int ks = 0; ks < 2; ks++)
#pragma unroll
      for (int nt = 0; nt < 4; nt++) {
        bf16x8 kf = *(const bf16x8*)(kb + (size_t)(kv0 + nt * 16 + c16) * 64 + ks * 32 + quad * 8);
        sacc[nt] = __builtin_amdgcn_mfma_f32_16x16x32_bf16(kf, qf[ks], sacc[nt], 0, 0, 0);
      }
    // ---- prefetch V A-frags for ks2=0 (fly during softmax) ----
    bf16x8 vf0[4];
#pragma unroll
    for (int nt = 0; nt < 4; nt++)
      vf0[nt] = *(const bf16x8*)(vb + (size_t)(nt * 16 + c16) * 2048 + kv0 + quad * 8);
    // ---- p = exp(m*s/8); per-lane l partial (no max: |s*m/8| small) ----
#pragma unroll
    for (int nt = 0; nt < 4; nt++)
#pragma unroll
      for (int rr = 0; rr < 4; rr++) {
        float p = __expf(sacc[nt][rr] * fscale);
        sacc[nt][rr] = p;
        lsum += p;
      }
    // ---- pack P^T rows: lane holds P[q=c16][kv=nt*16+quad*4+rr] ----
#pragma unroll
    for (int nt = 0; nt < 4; nt++) {
      ushort4 pk = make_ushort4(f2bf(sacc[nt][0]), f2bf(sacc[nt][1]),
                                f2bf(sacc[nt][2]), f2bf(sacc[nt][3]));
      *(ushort4*)&Pl[w][c16][nt * 16 + quad * 4] = pk;
    }
    // ---- O^T += V^T P^T (wave-private LDS, DS in-order; no barrier) ----
    bf16x8 vf1[4];
#pragma unroll
    for (int nt = 0; nt < 4; nt++)
      vf1[nt] = *(const bf16x8*)(vb + (size_t)(nt * 16 + c16) * 2048 + kv0 + 32 + quad * 8);
    {
      bf16x8 pf = *(const bf16x8*)&Pl[w][c16][quad * 8];
#pragma unroll
      for (int nt = 0; nt < 4; nt++)
        oacc[nt] = __builtin_amdgcn_mfma_f32_16x16x32_bf16(vf0[nt], pf, oacc[nt], 0, 0, 0);
    }
    {
      bf16x8 pf = *(const bf16x8*)&Pl[w][c16][32 + quad * 8];
#pragma unroll
      for (int nt = 0; nt < 4; nt++)
        oacc[nt] = __builtin_amdgcn_mfma_f32_16x16x32_bf16(vf1[nt], pf, oacc[nt], 0, 0, 0);
    }
  }

  // ---- l: sum the 4 lanes sharing c16 (quads) ----
  lsum += __shfl_xor(lsum, 16);
  lsum += __shfl_xor(lsum, 32);

  // ---- publish partials, combine across kv-split ----
#pragma unroll
  for (int nt = 0; nt < 4; nt++)
#pragma unroll
    for (int rr = 0; rr < 4; rr++)
      Os[w][nt * 16 + quad * 4 + rr][c16] = oacc[nt][rr];
  if (quad == 0) Ls[w][c16] = lsum;
  __syncthreads();

#pragma unroll
  for (int e = tid; e < 1024; e += 512) {
    const int qq = e >> 6, d = e & 63;
    float s = 0.0f, l = 0.0f;
#pragma unroll
    for (int ww = 0; ww < 8; ww++) { s += Os[ww][d][qq]; l += Ls[ww][qq]; }
    y[(size_t)(b * 2048 + q0 + qq) * 64 + d] = s / l;
  }
}

// ---------------------------------------------------------------------------
extern "C" void kernel_launch(void* const* d_in, const int* in_sizes, int n_in,
                              void* d_out, int out_size, void* d_ws, size_t ws_size,
                              hipStream_t stream) {
  (void)in_sizes; (void)n_in; (void)out_size; (void)ws_size;
  const float* q  = (const float*)d_in[0];
  const float* k  = (const float*)d_in[1];
  const float* v  = (const float*)d_in[2];
  const float* m  = (const float*)d_in[3];
  const float* Wq = (const float*)d_in[4];
  const float* Wk = (const float*)d_in[5];
  const float* Wv = (const float*)d_in[6];
  float* y = (float*)d_out;

  u16* qh  = (u16*)d_ws;          // [4][2048][64] bf16  (1 MB)
  u16* kh  = qh + 524288;         // [4][2048][64] bf16  (1 MB)
  u16* vhT = kh + 524288;         // [4][64][2048] bf16  (1 MB)
  u16* Wbf = vhT + 524288;        // [3][64][1024] bf16  (384 KB)

  wcvt_kernel<<<dim3(192), 256, 0, stream>>>(Wq, Wk, Wv, Wbf);
  proj_kernel<<<dim3(1536), 256, 0, stream>>>(q, k, v, Wbf, qh, kh, vhT);
  attn_kernel<<<dim3(128, 4), 512, 0, stream>>>(qh, kh, vhT, m, y);
}

// Round 6
// 167.581 us; speedup vs baseline: 1.0451x; 1.0451x over previous
//
#include <hip/hip_runtime.h>
#include <stdint.h>

// ---------------------------------------------------------------------------
// MaskedAttentionHead: B=4, S=2048, d_model=1024, d_k=64
// R14 == R13 resubmit (R5 bench was GPUAcquisitionTimeout — broker infra,
// kernel never ran; no new evidence, so no design change).
// R13: proj reverted to R8 exactly (measured best 40.2 first-dispatch; R9-R12
// falsified occupancy/pipeline-depth/persistence theories — all variants land
// 40-48us at ~2.2 TB/s consumed read, a platform read-path wall ~1.4x off the
// plausible pure-read ceiling ~3.15 TB/s). Pivot to attn (<=41us, never
// profiled): (a) cross-c software pipeline of K ks=0 frags (prefetch during
// exp/pack/PV, +16 VGPR), (b) T5 s_setprio(1) around MFMA clusters (attn
// regime: no kv-loop barriers -> waves phase-diverse, m191 +4-7%).
// wcvt unchanged.
// ---------------------------------------------------------------------------

typedef __bf16 bf16x8 __attribute__((ext_vector_type(8)));
typedef float  f32x4  __attribute__((ext_vector_type(4)));
typedef unsigned short u16;
typedef unsigned int   u32;

__device__ __forceinline__ u16 f2bf(float f) {
  u32 u = __float_as_uint(f);
  u += 0x7fffu + ((u >> 16) & 1u);          // round-to-nearest-even
  return (u16)(u >> 16);
}

// --------------------------- W fp32 -> bf16 --------------------------------
__global__ __launch_bounds__(256) void wcvt_kernel(
    const float* __restrict__ Wq, const float* __restrict__ Wk,
    const float* __restrict__ Wv, u16* __restrict__ Wbf) {
  int i = (blockIdx.x * 256 + threadIdx.x) * 4;   // 3*64*1024 = 196608 total
  const float* src = (i < 65536) ? Wq : (i < 131072) ? Wk : Wv;
  int off = i & 65535;
  float4 f = *(const float4*)(src + off);
  *(ushort4*)(Wbf + i) = make_ushort4(f2bf(f.x), f2bf(f.y), f2bf(f.z), f2bf(f.w));
}

// --------------------------- projections -----------------------------------
// R8 structure (verified fastest): grid 1536 (which = bx%3, 512 row-blocks),
// block 256 (4 waves), 2 blocks/CU. Block owns 16 rows. Wave w stages rows
// w*4..w*4+3 (16 contiguous float4 loads -> 64 named VGPRs -> cvt -> LDS).
// W quarter-panel 64x256 bf16 in LDS, restaged per qq. Combine 4 k-partials
// via os overlay on xl.
__global__ __launch_bounds__(256, 2) void proj_kernel(
    const float* __restrict__ q, const float* __restrict__ k,
    const float* __restrict__ v, const u16* __restrict__ Wbf,
    u16* __restrict__ qh, u16* __restrict__ kh, u16* __restrict__ vhT) {
  __shared__ u16 xl[16][1032];   // X tile bf16; stride 2064 B -> 2-way (free)
  __shared__ u16 wq[64][264];    // W quarter;  stride  528 B -> 2-way (free)
  const int tid = threadIdx.x;
  const int lane = tid & 63, w = tid >> 6;
  const int c16 = lane & 15, quad = lane >> 4;
  const int which = blockIdx.x % 3;
  const int r0 = (blockIdx.x / 3) * 16;
  const float* X = (which == 0) ? q : (which == 1) ? k : v;
  const u16* wsrc = Wbf + which * 65536;

  // ---- issue W quarter-0 loads first (oldest -> retire before X burst) ----
  bf16x8 wld[8];
#pragma unroll
  for (int i = 0; i < 8; i++) {
    int f = i * 2048 + tid * 8;              // 16384 u16 = 64 x 256
    wld[i] = *(const bf16x8*)(wsrc + (size_t)(f >> 8) * 1024 + (f & 255));
  }
  // ---- X burst: 16 contiguous 1-KB float4 loads (wave's 4 rows) ----
  const float* xgw = X + (size_t)(r0 + w * 4) * 1024 + lane * 4;
  float4 ar[16];
#pragma unroll
  for (int i = 0; i < 16; i++) ar[i] = *(const float4*)(xgw + i * 256);

  // ---- W q0 -> LDS (waits only the 8 W loads: vmcnt(16)) ----
#pragma unroll
  for (int i = 0; i < 8; i++) {
    int f = i * 2048 + tid * 8;
    *(bf16x8*)&wq[f >> 8][f & 255] = wld[i];
  }
  // ---- X cvt -> LDS (waits vmcnt(0)) ----
#pragma unroll
  for (int i = 0; i < 16; i++) {
    ushort4 pk = make_ushort4(f2bf(ar[i].x), f2bf(ar[i].y),
                              f2bf(ar[i].z), f2bf(ar[i].w));
    *(ushort4*)&xl[w * 4 + (i >> 2)][(i & 3) * 256 + lane * 4] = pk;
  }
  __syncthreads();

  f32x4 acc[4];
#pragma unroll
  for (int nt = 0; nt < 4; nt++)
#pragma unroll
    for (int j = 0; j < 4; j++) acc[nt][j] = 0.0f;

#pragma unroll
  for (int qq = 0; qq < 4; qq++) {
    // ---- compute this quarter: wave's 64-wide k-slice, 8 MFMA ----
#pragma unroll
    for (int ks = 0; ks < 2; ks++) {
      const int kin = w * 64 + ks * 32 + quad * 8;       // col within quarter
      bf16x8 af = *(const bf16x8*)&xl[c16][qq * 256 + kin];
#pragma unroll
      for (int nt = 0; nt < 4; nt++) {
        bf16x8 wf = *(const bf16x8*)&wq[nt * 16 + c16][kin];
        acc[nt] = __builtin_amdgcn_mfma_f32_16x16x32_bf16(af, wf, acc[nt], 0, 0, 0);
      }
    }
    // ---- restage W quarter qq+1 ----
    if (qq < 3) {
      __syncthreads();                       // all waves done reading wq
#pragma unroll
      for (int i = 0; i < 8; i++) {
        int f = i * 2048 + tid * 8;
        *(bf16x8*)&wq[f >> 8][f & 255] =
            *(const bf16x8*)(wsrc + (size_t)(f >> 8) * 1024 + (qq + 1) * 256 + (f & 255));
      }
      __syncthreads();
    }
  }

  // ---- combine 4 k-partials via os overlay on xl (xl dead) ----
  __syncthreads();
  float* osp = (float*)&xl[0][0];            // os[w][16][64] = 16 KB
#pragma unroll
  for (int nt = 0; nt < 4; nt++)
#pragma unroll
    for (int rr = 0; rr < 4; rr++)
      osp[((size_t)w * 16 + quad * 4 + rr) * 64 + nt * 16 + c16] = acc[nt][rr];
  __syncthreads();

  if (which == 2) {
    const int col = tid >> 2, s4 = (tid & 3) * 4;
    float s[4];
#pragma unroll
    for (int rr = 0; rr < 4; rr++)
      s[rr] = osp[(0 * 16 + s4 + rr) * 64 + col] + osp[(1 * 16 + s4 + rr) * 64 + col] +
              osp[(2 * 16 + s4 + rr) * 64 + col] + osp[(3 * 16 + s4 + rr) * 64 + col];
    const int bb = r0 >> 11, s0 = (r0 & 2047) + s4;
    ushort4 pk = make_ushort4(f2bf(s[0]), f2bf(s[1]), f2bf(s[2]), f2bf(s[3]));
    *(ushort4*)(vhT + ((size_t)bb * 64 + col) * 2048 + s0) = pk;
  } else {
    u16* out = (which == 0) ? qh : kh;
    const int row = tid >> 4, c4 = (tid & 15) * 4;
    float s[4];
#pragma unroll
    for (int j = 0; j < 4; j++)
      s[j] = osp[(0 * 16 + row) * 64 + c4 + j] + osp[(1 * 16 + row) * 64 + c4 + j] +
             osp[(2 * 16 + row) * 64 + c4 + j] + osp[(3 * 16 + row) * 64 + c4 + j];
    ushort4 pk = make_ushort4(f2bf(s[0]), f2bf(s[1]), f2bf(s[2]), f2bf(s[3]));
    *(ushort4*)(out + (size_t)(r0 + row) * 64 + c4) = pk;
  }
}

// --------------------------- flash attention --------------------------------
// grid (128,4), block 512 (8 waves, kv-split 8). Transposed math:
//   S^T[kv][q] = K Q^T  (A=K-frag, B=Q-frag, both natural row-major)
//   O^T[d][q]  = V^T P^T (A=vhT-frag, B=P-frag from packed LDS)
// Mask scale is per-column q = c16 -> one scalar/lane. No kv-loop barriers.
// R13: cross-c K-prefetch (ks=0 frags for c+1 issued before exp/pack/PV so
// their L2 latency hides under VALU+PV) + s_setprio(1) around MFMA clusters.
__global__ __launch_bounds__(512, 4) void attn_kernel(
    const u16* __restrict__ qh, const u16* __restrict__ kh,
    const u16* __restrict__ vhT, const float* __restrict__ m,
    float* __restrict__ y) {
  __shared__ float Os[8][64][17];    // [w][d][q] +1 pad        34.8 KB
  __shared__ float Ls[8][16];
  __shared__ u16  Pl[8][16][68];     // [w][q][kv] +4 pad       17.4 KB
  const int tid = threadIdx.x;
  const int lane = tid & 63, w = tid >> 6;
  const int c16 = lane & 15, quad = lane >> 4;
  const int b = blockIdx.y;
  const int q0 = blockIdx.x * 16;

  // Q B-frags (n=q=c16, k=d contiguous), persistent
  bf16x8 qf[2];
  {
    const u16* qp = qh + (size_t)(b * 2048 + q0 + c16) * 64 + quad * 8;
    qf[0] = *(const bf16x8*)qp;
    qf[1] = *(const bf16x8*)(qp + 32);
  }
  const float fscale = 0.125f * m[b * 2048 + q0 + c16];

  f32x4 oacc[4];
#pragma unroll
  for (int nt = 0; nt < 4; nt++)
#pragma unroll
    for (int j = 0; j < 4; j++) oacc[nt][j] = 0.0f;
  float lsum = 0.0f;

  const u16* kb = kh + (size_t)b * 131072;
  const u16* vb = vhT + (size_t)b * 131072;

  // ---- prologue: K ks=0 frags for c=0 ----
  bf16x8 kfc[4];
#pragma unroll
  for (int nt = 0; nt < 4; nt++)
    kfc[nt] = *(const bf16x8*)(kb + (size_t)(w * 64 + nt * 16 + c16) * 64 + quad * 8);

  for (int c = 0; c < 4; c++) {
    const int kv0 = w * 64 + c * 512;
    // ---- S^T = K Q^T : ks=0 uses prefetched kfc ----
    f32x4 sacc[4];
#pragma unroll
    for (int nt = 0; nt < 4; nt++)
#pragma unroll
      for (int j = 0; j < 4; j++) sacc[nt][j] = 0.0f;
    __builtin_amdgcn_s_setprio(1);
#pragma unroll
    for (int nt = 0; nt < 4; nt++)
      sacc[nt] = __builtin_amdgcn_mfma_f32_16x16x32_bf16(kfc[nt], qf[0], sacc[nt], 0, 0, 0);
    __builtin_amdgcn_s_setprio(0);
    // ks=1 frags (this c)
    bf16x8 kf1[4];
#pragma unroll
    for (int nt = 0; nt < 4; nt++)
      kf1[nt] = *(const bf16x8*)(kb + (size_t)(kv0 + nt * 16 + c16) * 64 + 32 + quad * 8);
    // prefetch next c's ks=0 frags (dead-use on last iter; in-bounds via &3)
    {
      const int kvn = w * 64 + ((c + 1) & 3) * 512;
#pragma unroll
      for (int nt = 0; nt < 4; nt++)
        kfc[nt] = *(const bf16x8*)(kb + (size_t)(kvn + nt * 16 + c16) * 64 + quad * 8);
    }
    __builtin_amdgcn_s_setprio(1);
#pragma unroll
    for (int nt = 0; nt < 4; nt++)
      sacc[nt] = __builtin_amdgcn_mfma_f32_16x16x32_bf16(kf1[nt], qf[1], sacc[nt], 0, 0, 0);
    __builtin_amdgcn_s_setprio(0);
    // ---- prefetch V A-frags for ks2=0 (fly during softmax) ----
    bf16x8 vf0[4];
#pragma unroll
    for (int nt = 0; nt < 4; nt++)
      vf0[nt] = *(const bf16x8*)(vb + (size_t)(nt * 16 + c16) * 2048 + kv0 + quad * 8);
    // ---- p = exp(m*s/8); per-lane l partial (no max: |s*m/8| small) ----
#pragma unroll
    for (int nt = 0; nt < 4; nt++)
#pragma unroll
      for (int rr = 0; rr < 4; rr++) {
        float p = __expf(sacc[nt][rr] * fscale);
        sacc[nt][rr] = p;
        lsum += p;
      }
    // ---- pack P^T rows: lane holds P[q=c16][kv=nt*16+quad*4+rr] ----
#pragma unroll
    for (int nt = 0; nt < 4; nt++) {
      ushort4 pk = make_ushort4(f2bf(sacc[nt][0]), f2bf(sacc[nt][1]),
                                f2bf(sacc[nt][2]), f2bf(sacc[nt][3]));
      *(ushort4*)&Pl[w][c16][nt * 16 + quad * 4] = pk;
    }
    // ---- O^T += V^T P^T (wave-private LDS, DS in-order; no barrier) ----
    bf16x8 vf1[4];
#pragma unroll
    for (int nt = 0; nt < 4; nt++)
      vf1[nt] = *(const bf16x8*)(vb + (size_t)(nt * 16 + c16) * 2048 + kv0 + 32 + quad * 8);
    {
      bf16x8 pf = *(const bf16x8*)&Pl[w][c16][quad * 8];
      __builtin_amdgcn_s_setprio(1);
#pragma unroll
      for (int nt = 0; nt < 4; nt++)
        oacc[nt] = __builtin_amdgcn_mfma_f32_16x16x32_bf16(vf0[nt], pf, oacc[nt], 0, 0, 0);
      __builtin_amdgcn_s_setprio(0);
    }
    {
      bf16x8 pf = *(const bf16x8*)&Pl[w][c16][32 + quad * 8];
      __builtin_amdgcn_s_setprio(1);
#pragma unroll
      for (int nt = 0; nt < 4; nt++)
        oacc[nt] = __builtin_amdgcn_mfma_f32_16x16x32_bf16(vf1[nt], pf, oacc[nt], 0, 0, 0);
      __builtin_amdgcn_s_setprio(0);
    }
  }

  // ---- l: sum the 4 lanes sharing c16 (quads) ----
  lsum += __shfl_xor(lsum, 16);
  lsum += __shfl_xor(lsum, 32);

  // ---- publish partials, combine across kv-split ----
#pragma unroll
  for (int nt = 0; nt < 4; nt++)
#pragma unroll
    for (int rr = 0; rr < 4; rr++)
      Os[w][nt * 16 + quad * 4 + rr][c16] = oacc[nt][rr];
  if (quad == 0) Ls[w][c16] = lsum;
  __syncthreads();

#pragma unroll
  for (int e = tid; e < 1024; e += 512) {
    const int qq = e >> 6, d = e & 63;
    float s = 0.0f, l = 0.0f;
#pragma unroll
    for (int ww = 0; ww < 8; ww++) { s += Os[ww][d][qq]; l += Ls[ww][qq]; }
    y[(size_t)(b * 2048 + q0 + qq) * 64 + d] = s / l;
  }
}

// ---------------------------------------------------------------------------
extern "C" void kernel_launch(void* const* d_in, const int* in_sizes, int n_in,
                              void* d_out, int out_size, void* d_ws, size_t ws_size,
                              hipStream_t stream) {
  (void)in_sizes; (void)n_in; (void)out_size; (void)ws_size;
  const float* q  = (const float*)d_in[0];
  const float* k  = (const float*)d_in[1];
  const float* v  = (const float*)d_in[2];
  const float* m  = (const float*)d_in[3];
  const float* Wq = (const float*)d_in[4];
  const float* Wk = (const float*)d_in[5];
  const float* Wv = (const float*)d_in[6];
  float* y = (float*)d_out;

  u16* qh  = (u16*)d_ws;          // [4][2048][64] bf16  (1 MB)
  u16* kh  = qh + 524288;         // [4][2048][64] bf16  (1 MB)
  u16* vhT = kh + 524288;         // [4][64][2048] bf16  (1 MB)
  u16* Wbf = vhT + 524288;        // [3][64][1024] bf16  (384 KB)

  wcvt_kernel<<<dim3(192), 256, 0, stream>>>(Wq, Wk, Wv, Wbf);
  proj_kernel<<<dim3(1536), 256, 0, stream>>>(q, k, v, Wbf, qh, kh, vhT);
  attn_kernel<<<dim3(128, 4), 512, 0, stream>>>(qh, kh, vhT, m, y);
}

// Round 7
// 155.956 us; speedup vs baseline: 1.1230x; 1.0745x over previous
//
#include <hip/hip_runtime.h>
#include <stdint.h>

// ---------------------------------------------------------------------------
// MaskedAttentionHead: B=4, S=2048, d_model=1024, d_k=64
// R15: proj/wcvt = R8 revert (verified: proj dropped below the 40.4us fill
// cutoff in R14). attn rewritten for LOAD CONCURRENCY: old structure had
// 16 waves/CU x 16 loads x 16B = 4KB/CU in flight vs ~17KB needed to
// saturate L2 feed (135 GB/s/CU x ~125ns) -> 4x short, matching its
// inferred ~40us. VGPR cap (bounds 512,4 => 128) forbids deeper register
// prefetch (R9: compiler serializes, won't spill); grid 512 = 2 blk/CU
// forbids more waves. Fix: K/V via global_load_lds into per-wave-private
// double-buffered LDS (in-flight lives in the DMA queue, 0 VGPR), 8 c-iters
// x 32 kv rows, counted vmcnt(8)/wave, NO barriers in the kv loop
// (wave-private buffers -> no R11 lockstep). LDS 145.5KB -> 1 blk/CU but
// 64KB/CU in flight. Os overlaid on staging area post-loop (barrier before
// publish). Swizzle rule 21: linear LDS dest + inverse-XOR global source +
// XOR ds_read (unit^=(row&7) K, ^=(row&3) V). Numerics identical.
// Predict: attn ~40 -> 10-16us, total 167.6 -> ~140-150.
// ---------------------------------------------------------------------------

typedef __bf16 bf16x8 __attribute__((ext_vector_type(8)));
typedef float  f32x4  __attribute__((ext_vector_type(4)));
typedef unsigned short u16;
typedef unsigned int   u32;

__device__ __forceinline__ u16 f2bf(float f) {
  u32 u = __float_as_uint(f);
  u += 0x7fffu + ((u >> 16) & 1u);          // round-to-nearest-even
  return (u16)(u >> 16);
}

// --------------------------- W fp32 -> bf16 --------------------------------
__global__ __launch_bounds__(256) void wcvt_kernel(
    const float* __restrict__ Wq, const float* __restrict__ Wk,
    const float* __restrict__ Wv, u16* __restrict__ Wbf) {
  int i = (blockIdx.x * 256 + threadIdx.x) * 4;   // 3*64*1024 = 196608 total
  const float* src = (i < 65536) ? Wq : (i < 131072) ? Wk : Wv;
  int off = i & 65535;
  float4 f = *(const float4*)(src + off);
  *(ushort4*)(Wbf + i) = make_ushort4(f2bf(f.x), f2bf(f.y), f2bf(f.z), f2bf(f.w));
}

// --------------------------- projections -----------------------------------
// R8 structure (verified fastest): grid 1536 (which = bx%3, 512 row-blocks),
// block 256 (4 waves), 2 blocks/CU. Block owns 16 rows. Wave w stages rows
// w*4..w*4+3 (16 contiguous float4 loads -> 64 named VGPRs -> cvt -> LDS).
// W quarter-panel 64x256 bf16 in LDS, restaged per qq. Combine 4 k-partials
// via os overlay on xl.
__global__ __launch_bounds__(256, 2) void proj_kernel(
    const float* __restrict__ q, const float* __restrict__ k,
    const float* __restrict__ v, const u16* __restrict__ Wbf,
    u16* __restrict__ qh, u16* __restrict__ kh, u16* __restrict__ vhT) {
  __shared__ u16 xl[16][1032];   // X tile bf16; stride 2064 B -> 2-way (free)
  __shared__ u16 wq[64][264];    // W quarter;  stride  528 B -> 2-way (free)
  const int tid = threadIdx.x;
  const int lane = tid & 63, w = tid >> 6;
  const int c16 = lane & 15, quad = lane >> 4;
  const int which = blockIdx.x % 3;
  const int r0 = (blockIdx.x / 3) * 16;
  const float* X = (which == 0) ? q : (which == 1) ? k : v;
  const u16* wsrc = Wbf + which * 65536;

  // ---- issue W quarter-0 loads first (oldest -> retire before X burst) ----
  bf16x8 wld[8];
#pragma unroll
  for (int i = 0; i < 8; i++) {
    int f = i * 2048 + tid * 8;              // 16384 u16 = 64 x 256
    wld[i] = *(const bf16x8*)(wsrc + (size_t)(f >> 8) * 1024 + (f & 255));
  }
  // ---- X burst: 16 contiguous 1-KB float4 loads (wave's 4 rows) ----
  const float* xgw = X + (size_t)(r0 + w * 4) * 1024 + lane * 4;
  float4 ar[16];
#pragma unroll
  for (int i = 0; i < 16; i++) ar[i] = *(const float4*)(xgw + i * 256);

  // ---- W q0 -> LDS (waits only the 8 W loads: vmcnt(16)) ----
#pragma unroll
  for (int i = 0; i < 8; i++) {
    int f = i * 2048 + tid * 8;
    *(bf16x8*)&wq[f >> 8][f & 255] = wld[i];
  }
  // ---- X cvt -> LDS (waits vmcnt(0)) ----
#pragma unroll
  for (int i = 0; i < 16; i++) {
    ushort4 pk = make_ushort4(f2bf(ar[i].x), f2bf(ar[i].y),
                              f2bf(ar[i].z), f2bf(ar[i].w));
    *(ushort4*)&xl[w * 4 + (i >> 2)][(i & 3) * 256 + lane * 4] = pk;
  }
  __syncthreads();

  f32x4 acc[4];
#pragma unroll
  for (int nt = 0; nt < 4; nt++)
#pragma unroll
    for (int j = 0; j < 4; j++) acc[nt][j] = 0.0f;

#pragma unroll
  for (int qq = 0; qq < 4; qq++) {
    // ---- compute this quarter: wave's 64-wide k-slice, 8 MFMA ----
#pragma unroll
    for (int ks = 0; ks < 2; ks++) {
      const int kin = w * 64 + ks * 32 + quad * 8;       // col within quarter
      bf16x8 af = *(const bf16x8*)&xl[c16][qq * 256 + kin];
#pragma unroll
      for (int nt = 0; nt < 4; nt++) {
        bf16x8 wf = *(const bf16x8*)&wq[nt * 16 + c16][kin];
        acc[nt] = __builtin_amdgcn_mfma_f32_16x16x32_bf16(af, wf, acc[nt], 0, 0, 0);
      }
    }
    // ---- restage W quarter qq+1 ----
    if (qq < 3) {
      __syncthreads();                       // all waves done reading wq
#pragma unroll
      for (int i = 0; i < 8; i++) {
        int f = i * 2048 + tid * 8;
        *(bf16x8*)&wq[f >> 8][f & 255] =
            *(const bf16x8*)(wsrc + (size_t)(f >> 8) * 1024 + (qq + 1) * 256 + (f & 255));
      }
      __syncthreads();
    }
  }

  // ---- combine 4 k-partials via os overlay on xl (xl dead) ----
  __syncthreads();
  float* osp = (float*)&xl[0][0];            // os[w][16][64] = 16 KB
#pragma unroll
  for (int nt = 0; nt < 4; nt++)
#pragma unroll
    for (int rr = 0; rr < 4; rr++)
      osp[((size_t)w * 16 + quad * 4 + rr) * 64 + nt * 16 + c16] = acc[nt][rr];
  __syncthreads();

  if (which == 2) {
    const int col = tid >> 2, s4 = (tid & 3) * 4;
    float s[4];
#pragma unroll
    for (int rr = 0; rr < 4; rr++)
      s[rr] = osp[(0 * 16 + s4 + rr) * 64 + col] + osp[(1 * 16 + s4 + rr) * 64 + col] +
              osp[(2 * 16 + s4 + rr) * 64 + col] + osp[(3 * 16 + s4 + rr) * 64 + col];
    const int bb = r0 >> 11, s0 = (r0 & 2047) + s4;
    ushort4 pk = make_ushort4(f2bf(s[0]), f2bf(s[1]), f2bf(s[2]), f2bf(s[3]));
    *(ushort4*)(vhT + ((size_t)bb * 64 + col) * 2048 + s0) = pk;
  } else {
    u16* out = (which == 0) ? qh : kh;
    const int row = tid >> 4, c4 = (tid & 15) * 4;
    float s[4];
#pragma unroll
    for (int j = 0; j < 4; j++)
      s[j] = osp[(0 * 16 + row) * 64 + c4 + j] + osp[(1 * 16 + row) * 64 + c4 + j] +
             osp[(2 * 16 + row) * 64 + c4 + j] + osp[(3 * 16 + row) * 64 + c4 + j];
    ushort4 pk = make_ushort4(f2bf(s[0]), f2bf(s[1]), f2bf(s[2]), f2bf(s[3]));
    *(ushort4*)(out + (size_t)(r0 + row) * 64 + c4) = pk;
  }
}

// --------------------------- flash attention --------------------------------
// grid (128,4), block 512 (8 waves, kv-split 8 x c-loop 8, 32 kv rows/iter).
// Transposed math: S^T[kv][q] = K Q^T ; O^T[d][q] = V^T P^T.
// K/V staged per-wave via global_load_lds, double-buffered, vmcnt(8) counted,
// no barriers in the kv loop. LDS per (wave,buf): K [32][8u] 4KB + V [64][4u]
// 4KB (u = 16B unit, XOR-swizzled). Mask scale per-column q = c16.
__global__ __launch_bounds__(512, 2) void attn_kernel(
    const u16* __restrict__ qh, const u16* __restrict__ kh,
    const u16* __restrict__ vhT, const float* __restrict__ m,
    float* __restrict__ y) {
  __shared__ u16  kvs[8][2][4096];   // [w][buf][K 2048 | V 2048]   128 KB
  __shared__ u16  Pl[8][16][68];     // [w][q][kv] +4 pad          17.0 KB
  __shared__ float Ls[8][16];        //                             0.5 KB
  const int tid = threadIdx.x;
  const int lane = tid & 63, w = tid >> 6;
  const int c16 = lane & 15, quad = lane >> 4;
  const int b = blockIdx.y;
  const int q0 = blockIdx.x * 16;

  // Q B-frags (n=q=c16, k=d contiguous), persistent
  bf16x8 qf[2];
  {
    const u16* qp = qh + (size_t)(b * 2048 + q0 + c16) * 64 + quad * 8;
    qf[0] = *(const bf16x8*)qp;
    qf[1] = *(const bf16x8*)(qp + 32);
  }
  const float fscale = 0.125f * m[b * 2048 + q0 + c16];

  f32x4 oacc[4];
#pragma unroll
  for (int nt = 0; nt < 4; nt++)
#pragma unroll
    for (int j = 0; j < 4; j++) oacc[nt][j] = 0.0f;
  float lsum = 0.0f;

  const u16* kb = kh + (size_t)b * 131072;
  const u16* vb = vhT + (size_t)b * 131072;

  // Stage one 32-row kv chunk into kvs[w][bf_]: 8x global_load_lds(16B).
  // LDS dest = wave-uniform base (+lane*16B by HW, linear). Global source
  // carries the inverse XOR swizzle so swizzled ds_reads see natural data.
#define STAGEKV(bf_, kv0_)                                                    \
  {                                                                           \
    _Pragma("unroll") for (int i = 0; i < 4; i++) {                           \
      const int ri_ = i * 8 + (lane >> 3), ui_ = lane & 7;                    \
      const u16* gp_ = kb + (size_t)((kv0_) + ri_) * 64 + ((ui_ ^ (ri_ & 7)) << 3); \
      __builtin_amdgcn_global_load_lds(                                       \
          (const __attribute__((address_space(1))) u32*)gp_,                  \
          (__attribute__((address_space(3))) u32*)&kvs[w][bf_][i * 512],      \
          16, 0, 0);                                                          \
    }                                                                         \
    _Pragma("unroll") for (int i = 0; i < 4; i++) {                           \
      const int ri_ = i * 16 + (lane >> 2), ui_ = lane & 3;                   \
      const u16* gp_ = vb + (size_t)ri_ * 2048 + (kv0_) + ((ui_ ^ (ri_ & 3)) << 3); \
      __builtin_amdgcn_global_load_lds(                                       \
          (const __attribute__((address_space(1))) u32*)gp_,                  \
          (__attribute__((address_space(3))) u32*)&kvs[w][bf_][2048 + i * 512], \
          16, 0, 0);                                                          \
    }                                                                         \
  }

  // ---- prologue: stage chunk 0 ----
  STAGEKV(0, w * 32);

  int bfv = 0;
#pragma unroll 1
  for (int c = 0; c < 8; c++) {
    // issue next chunk; wait current (its 8 DMAs are the oldest outstanding)
    if (c < 7) {
      STAGEKV(bfv ^ 1, (c + 1) * 256 + w * 32);
      asm volatile("s_waitcnt vmcnt(8)" ::: "memory");
    } else {
      asm volatile("s_waitcnt vmcnt(0)" ::: "memory");
    }
    __builtin_amdgcn_sched_barrier(0);
    const u16* kl = &kvs[w][bfv][0];

    // ---- S^T = K Q^T : 2 nt x 2 ks MFMA from swizzled LDS ----
    f32x4 sacc[2];
#pragma unroll
    for (int nt = 0; nt < 2; nt++)
#pragma unroll
      for (int j = 0; j < 4; j++) sacc[nt][j] = 0.0f;
    __builtin_amdgcn_s_setprio(1);
#pragma unroll
    for (int ks = 0; ks < 2; ks++)
#pragma unroll
      for (int nt = 0; nt < 2; nt++) {
        bf16x8 kf = *(const bf16x8*)(kl + (nt * 16 + c16) * 64 +
                                     (((ks * 4 + quad) ^ (c16 & 7)) << 3));
        sacc[nt] = __builtin_amdgcn_mfma_f32_16x16x32_bf16(kf, qf[ks], sacc[nt], 0, 0, 0);
      }
    __builtin_amdgcn_s_setprio(0);

    // ---- p = exp(m*s/8); per-lane l partial (no max: |s*m/8| small) ----
#pragma unroll
    for (int nt = 0; nt < 2; nt++)
#pragma unroll
      for (int rr = 0; rr < 4; rr++) {
        float p = __expf(sacc[nt][rr] * fscale);
        sacc[nt][rr] = p;
        lsum += p;
      }
    // ---- pack P^T rows: lane holds P[q=c16][kv=nt*16+quad*4+rr] ----
#pragma unroll
    for (int nt = 0; nt < 2; nt++) {
      ushort4 pk = make_ushort4(f2bf(sacc[nt][0]), f2bf(sacc[nt][1]),
                                f2bf(sacc[nt][2]), f2bf(sacc[nt][3]));
      *(ushort4*)&Pl[w][c16][nt * 16 + quad * 4] = pk;
    }
    // ---- O^T += V^T P^T (wave-private LDS, DS in-order; no barrier) ----
    {
      bf16x8 pf = *(const bf16x8*)&Pl[w][c16][quad * 8];
      __builtin_amdgcn_s_setprio(1);
#pragma unroll
      for (int nt = 0; nt < 4; nt++) {
        bf16x8 vf = *(const bf16x8*)(kl + 2048 + (nt * 16 + c16) * 32 +
                                     ((quad ^ (c16 & 3)) << 3));
        oacc[nt] = __builtin_amdgcn_mfma_f32_16x16x32_bf16(vf, pf, oacc[nt], 0, 0, 0);
      }
      __builtin_amdgcn_s_setprio(0);
    }
    bfv ^= 1;
  }
#undef STAGEKV

  // ---- l: sum the 4 lanes sharing c16 (quads) ----
  lsum += __shfl_xor(lsum, 16);
  lsum += __shfl_xor(lsum, 32);

  // ---- all waves done with kvs; overlay Os on it, combine kv-split ----
  __syncthreads();
  float* osp = (float*)&kvs[0][0][0];        // Os[8][64][17] = 34.8 KB
#pragma unroll
  for (int nt = 0; nt < 4; nt++)
#pragma unroll
    for (int rr = 0; rr < 4; rr++)
      osp[((size_t)w * 64 + nt * 16 + quad * 4 + rr) * 17 + c16] = oacc[nt][rr];
  if (quad == 0) Ls[w][c16] = lsum;
  __syncthreads();

#pragma unroll
  for (int e = tid; e < 1024; e += 512) {
    const int qq = e >> 6, d = e & 63;
    float s = 0.0f, l = 0.0f;
#pragma unroll
    for (int ww = 0; ww < 8; ww++) { s += osp[((size_t)ww * 64 + d) * 17 + qq]; l += Ls[ww][qq]; }
    y[(size_t)(b * 2048 + q0 + qq) * 64 + d] = s / l;
  }
}

// ---------------------------------------------------------------------------
extern "C" void kernel_launch(void* const* d_in, const int* in_sizes, int n_in,
                              void* d_out, int out_size, void* d_ws, size_t ws_size,
                              hipStream_t stream) {
  (void)in_sizes; (void)n_in; (void)out_size; (void)ws_size;
  const float* q  = (const float*)d_in[0];
  const float* k  = (const float*)d_in[1];
  const float* v  = (const float*)d_in[2];
  const float* m  = (const float*)d_in[3];
  const float* Wq = (const float*)d_in[4];
  const float* Wk = (const float*)d_in[5];
  const float* Wv = (const float*)d_in[6];
  float* y = (float*)d_out;

  u16* qh  = (u16*)d_ws;          // [4][2048][64] bf16  (1 MB)
  u16* kh  = qh + 524288;         // [4][2048][64] bf16  (1 MB)
  u16* vhT = kh + 524288;         // [4][64][2048] bf16  (1 MB)
  u16* Wbf = vhT + 524288;        // [3][64][1024] bf16  (384 KB)

  wcvt_kernel<<<dim3(192), 256, 0, stream>>>(Wq, Wk, Wv, Wbf);
  proj_kernel<<<dim3(1536), 256, 0, stream>>>(q, k, v, Wbf, qh, kh, vhT);
  attn_kernel<<<dim3(128, 4), 512, 0, stream>>>(qh, kh, vhT, m, y);
}

// Round 8
// 150.517 us; speedup vs baseline: 1.1635x; 1.0361x over previous
//
#include <hip/hip_runtime.h>
#include <stdint.h>

// ---------------------------------------------------------------------------
// MaskedAttentionHead: B=4, S=2048, d_model=1024, d_k=64
// R16: attn q-tile 16 -> 32 rows. R15 post-mortem: LDS-DMA attn = ~28us =
// 2 sequential rounds (512 blocks x 145.5KB LDS = 1 blk/CU) x ~14us, each
// round staging the full 512KB K/V per block. Halve traffic: 256 blocks
// (grid 64x4) = 1 round, each staged byte feeds 2x MFMA (g=0/1 q-column
// groups). Staging/swizzle/vmcnt ledger byte-identical to R15 (proven);
// only the g dimension is new. Predict attn ~28 -> ~14-17us, total
// 155.96 -> ~142-147. proj/wcvt = R8 (verified best, unchanged).
// ---------------------------------------------------------------------------

typedef __bf16 bf16x8 __attribute__((ext_vector_type(8)));
typedef float  f32x4  __attribute__((ext_vector_type(4)));
typedef unsigned short u16;
typedef unsigned int   u32;

__device__ __forceinline__ u16 f2bf(float f) {
  u32 u = __float_as_uint(f);
  u += 0x7fffu + ((u >> 16) & 1u);          // round-to-nearest-even
  return (u16)(u >> 16);
}

// --------------------------- W fp32 -> bf16 --------------------------------
__global__ __launch_bounds__(256) void wcvt_kernel(
    const float* __restrict__ Wq, const float* __restrict__ Wk,
    const float* __restrict__ Wv, u16* __restrict__ Wbf) {
  int i = (blockIdx.x * 256 + threadIdx.x) * 4;   // 3*64*1024 = 196608 total
  const float* src = (i < 65536) ? Wq : (i < 131072) ? Wk : Wv;
  int off = i & 65535;
  float4 f = *(const float4*)(src + off);
  *(ushort4*)(Wbf + i) = make_ushort4(f2bf(f.x), f2bf(f.y), f2bf(f.z), f2bf(f.w));
}

// --------------------------- projections -----------------------------------
// R8 structure (verified fastest): grid 1536 (which = bx%3, 512 row-blocks),
// block 256 (4 waves), 2 blocks/CU. Block owns 16 rows. Wave w stages rows
// w*4..w*4+3 (16 contiguous float4 loads -> 64 named VGPRs -> cvt -> LDS).
// W quarter-panel 64x256 bf16 in LDS, restaged per qq. Combine 4 k-partials
// via os overlay on xl.
__global__ __launch_bounds__(256, 2) void proj_kernel(
    const float* __restrict__ q, const float* __restrict__ k,
    const float* __restrict__ v, const u16* __restrict__ Wbf,
    u16* __restrict__ qh, u16* __restrict__ kh, u16* __restrict__ vhT) {
  __shared__ u16 xl[16][1032];   // X tile bf16; stride 2064 B -> 2-way (free)
  __shared__ u16 wq[64][264];    // W quarter;  stride  528 B -> 2-way (free)
  const int tid = threadIdx.x;
  const int lane = tid & 63, w = tid >> 6;
  const int c16 = lane & 15, quad = lane >> 4;
  const int which = blockIdx.x % 3;
  const int r0 = (blockIdx.x / 3) * 16;
  const float* X = (which == 0) ? q : (which == 1) ? k : v;
  const u16* wsrc = Wbf + which * 65536;

  // ---- issue W quarter-0 loads first (oldest -> retire before X burst) ----
  bf16x8 wld[8];
#pragma unroll
  for (int i = 0; i < 8; i++) {
    int f = i * 2048 + tid * 8;              // 16384 u16 = 64 x 256
    wld[i] = *(const bf16x8*)(wsrc + (size_t)(f >> 8) * 1024 + (f & 255));
  }
  // ---- X burst: 16 contiguous 1-KB float4 loads (wave's 4 rows) ----
  const float* xgw = X + (size_t)(r0 + w * 4) * 1024 + lane * 4;
  float4 ar[16];
#pragma unroll
  for (int i = 0; i < 16; i++) ar[i] = *(const float4*)(xgw + i * 256);

  // ---- W q0 -> LDS (waits only the 8 W loads: vmcnt(16)) ----
#pragma unroll
  for (int i = 0; i < 8; i++) {
    int f = i * 2048 + tid * 8;
    *(bf16x8*)&wq[f >> 8][f & 255] = wld[i];
  }
  // ---- X cvt -> LDS (waits vmcnt(0)) ----
#pragma unroll
  for (int i = 0; i < 16; i++) {
    ushort4 pk = make_ushort4(f2bf(ar[i].x), f2bf(ar[i].y),
                              f2bf(ar[i].z), f2bf(ar[i].w));
    *(ushort4*)&xl[w * 4 + (i >> 2)][(i & 3) * 256 + lane * 4] = pk;
  }
  __syncthreads();

  f32x4 acc[4];
#pragma unroll
  for (int nt = 0; nt < 4; nt++)
#pragma unroll
    for (int j = 0; j < 4; j++) acc[nt][j] = 0.0f;

#pragma unroll
  for (int qq = 0; qq < 4; qq++) {
    // ---- compute this quarter: wave's 64-wide k-slice, 8 MFMA ----
#pragma unroll
    for (int ks = 0; ks < 2; ks++) {
      const int kin = w * 64 + ks * 32 + quad * 8;       // col within quarter
      bf16x8 af = *(const bf16x8*)&xl[c16][qq * 256 + kin];
#pragma unroll
      for (int nt = 0; nt < 4; nt++) {
        bf16x8 wf = *(const bf16x8*)&wq[nt * 16 + c16][kin];
        acc[nt] = __builtin_amdgcn_mfma_f32_16x16x32_bf16(af, wf, acc[nt], 0, 0, 0);
      }
    }
    // ---- restage W quarter qq+1 ----
    if (qq < 3) {
      __syncthreads();                       // all waves done reading wq
#pragma unroll
      for (int i = 0; i < 8; i++) {
        int f = i * 2048 + tid * 8;
        *(bf16x8*)&wq[f >> 8][f & 255] =
            *(const bf16x8*)(wsrc + (size_t)(f >> 8) * 1024 + (qq + 1) * 256 + (f & 255));
      }
      __syncthreads();
    }
  }

  // ---- combine 4 k-partials via os overlay on xl (xl dead) ----
  __syncthreads();
  float* osp = (float*)&xl[0][0];            // os[w][16][64] = 16 KB
#pragma unroll
  for (int nt = 0; nt < 4; nt++)
#pragma unroll
    for (int rr = 0; rr < 4; rr++)
      osp[((size_t)w * 16 + quad * 4 + rr) * 64 + nt * 16 + c16] = acc[nt][rr];
  __syncthreads();

  if (which == 2) {
    const int col = tid >> 2, s4 = (tid & 3) * 4;
    float s[4];
#pragma unroll
    for (int rr = 0; rr < 4; rr++)
      s[rr] = osp[(0 * 16 + s4 + rr) * 64 + col] + osp[(1 * 16 + s4 + rr) * 64 + col] +
              osp[(2 * 16 + s4 + rr) * 64 + col] + osp[(3 * 16 + s4 + rr) * 64 + col];
    const int bb = r0 >> 11, s0 = (r0 & 2047) + s4;
    ushort4 pk = make_ushort4(f2bf(s[0]), f2bf(s[1]), f2bf(s[2]), f2bf(s[3]));
    *(ushort4*)(vhT + ((size_t)bb * 64 + col) * 2048 + s0) = pk;
  } else {
    u16* out = (which == 0) ? qh : kh;
    const int row = tid >> 4, c4 = (tid & 15) * 4;
    float s[4];
#pragma unroll
    for (int j = 0; j < 4; j++)
      s[j] = osp[(0 * 16 + row) * 64 + c4 + j] + osp[(1 * 16 + row) * 64 + c4 + j] +
             osp[(2 * 16 + row) * 64 + c4 + j] + osp[(3 * 16 + row) * 64 + c4 + j];
    ushort4 pk = make_ushort4(f2bf(s[0]), f2bf(s[1]), f2bf(s[2]), f2bf(s[3]));
    *(ushort4*)(out + (size_t)(r0 + row) * 64 + c4) = pk;
  }
}

// --------------------------- flash attention --------------------------------
// grid (64,4) = 256 blocks (1/CU, ONE round), block 512 (8 waves, kv-split 8
// x c-loop 8, 32 kv rows/iter). Q-tile 32 rows = 2 column groups g (c16+g*16).
// Transposed math: S^T[kv][q] = K Q^T ; O^T[d][q] = V^T P^T.
// K/V staged per-wave via global_load_lds, double-buffered, vmcnt(8) counted,
// no barriers in the kv loop (staging identical to R15).
__global__ __launch_bounds__(512, 2) void attn_kernel(
    const u16* __restrict__ qh, const u16* __restrict__ kh,
    const u16* __restrict__ vhT, const float* __restrict__ m,
    float* __restrict__ y) {
  __shared__ u16  kvs[8][2][4096];   // [w][buf][K 2048 | V 2048]   128 KB
  __shared__ u16  Pl[8][32][36];     // [w][q 32][kv 32 +4 pad]    18.4 KB
  __shared__ float Ls[8][32];        //                             1.0 KB
  const int tid = threadIdx.x;
  const int lane = tid & 63, w = tid >> 6;
  const int c16 = lane & 15, quad = lane >> 4;
  const int b = blockIdx.y;
  const int q0 = blockIdx.x * 32;

  // Q B-frags (n=q=c16+g*16, k=d contiguous), persistent
  bf16x8 qf[2][2];                   // [ks][g]
  float fscale[2];
#pragma unroll
  for (int g = 0; g < 2; g++) {
    const u16* qp = qh + (size_t)(b * 2048 + q0 + g * 16 + c16) * 64 + quad * 8;
    qf[0][g] = *(const bf16x8*)qp;
    qf[1][g] = *(const bf16x8*)(qp + 32);
    fscale[g] = 0.125f * m[b * 2048 + q0 + g * 16 + c16];
  }

  f32x4 oacc[2][4];                  // [g][nt(d)]
#pragma unroll
  for (int g = 0; g < 2; g++)
#pragma unroll
    for (int nt = 0; nt < 4; nt++)
#pragma unroll
      for (int j = 0; j < 4; j++) oacc[g][nt][j] = 0.0f;
  float lsum[2] = {0.0f, 0.0f};

  const u16* kb = kh + (size_t)b * 131072;
  const u16* vb = vhT + (size_t)b * 131072;

  // Stage one 32-row kv chunk into kvs[w][bf_]: 8x global_load_lds(16B).
  // LDS dest = wave-uniform base (+lane*16B by HW, linear). Global source
  // carries the inverse XOR swizzle so swizzled ds_reads see natural data.
#define STAGEKV(bf_, kv0_)                                                    \
  {                                                                           \
    _Pragma("unroll") for (int i = 0; i < 4; i++) {                           \
      const int ri_ = i * 8 + (lane >> 3), ui_ = lane & 7;                    \
      const u16* gp_ = kb + (size_t)((kv0_) + ri_) * 64 + ((ui_ ^ (ri_ & 7)) << 3); \
      __builtin_amdgcn_global_load_lds(                                       \
          (const __attribute__((address_space(1))) u32*)gp_,                  \
          (__attribute__((address_space(3))) u32*)&kvs[w][bf_][i * 512],      \
          16, 0, 0);                                                          \
    }                                                                         \
    _Pragma("unroll") for (int i = 0; i < 4; i++) {                           \
      const int ri_ = i * 16 + (lane >> 2), ui_ = lane & 3;                   \
      const u16* gp_ = vb + (size_t)ri_ * 2048 + (kv0_) + ((ui_ ^ (ri_ & 3)) << 3); \
      __builtin_amdgcn_global_load_lds(                                       \
          (const __attribute__((address_space(1))) u32*)gp_,                  \
          (__attribute__((address_space(3))) u32*)&kvs[w][bf_][2048 + i * 512], \
          16, 0, 0);                                                          \
    }                                                                         \
  }

  // ---- prologue: stage chunk 0 ----
  STAGEKV(0, w * 32);

  int bfv = 0;
#pragma unroll 1
  for (int c = 0; c < 8; c++) {
    // issue next chunk; wait current (its 8 DMAs are the oldest outstanding)
    if (c < 7) {
      STAGEKV(bfv ^ 1, (c + 1) * 256 + w * 32);
      asm volatile("s_waitcnt vmcnt(8)" ::: "memory");
    } else {
      asm volatile("s_waitcnt vmcnt(0)" ::: "memory");
    }
    __builtin_amdgcn_sched_barrier(0);
    const u16* kl = &kvs[w][bfv][0];

    // ---- S^T = K Q^T : 2 nt x 2 ks x 2 g MFMA from swizzled LDS ----
    f32x4 sacc[2][2];                // [nt][g]
#pragma unroll
    for (int nt = 0; nt < 2; nt++)
#pragma unroll
      for (int g = 0; g < 2; g++)
#pragma unroll
        for (int j = 0; j < 4; j++) sacc[nt][g][j] = 0.0f;
    __builtin_amdgcn_s_setprio(1);
#pragma unroll
    for (int ks = 0; ks < 2; ks++)
#pragma unroll
      for (int nt = 0; nt < 2; nt++) {
        bf16x8 kf = *(const bf16x8*)(kl + (nt * 16 + c16) * 64 +
                                     (((ks * 4 + quad) ^ (c16 & 7)) << 3));
#pragma unroll
        for (int g = 0; g < 2; g++)
          sacc[nt][g] = __builtin_amdgcn_mfma_f32_16x16x32_bf16(kf, qf[ks][g], sacc[nt][g], 0, 0, 0);
      }
    __builtin_amdgcn_s_setprio(0);

    // ---- p = exp(m*s/8); per-lane l partial (no max: |s*m/8| small) ----
#pragma unroll
    for (int nt = 0; nt < 2; nt++)
#pragma unroll
      for (int g = 0; g < 2; g++)
#pragma unroll
        for (int rr = 0; rr < 4; rr++) {
          float p = __expf(sacc[nt][g][rr] * fscale[g]);
          sacc[nt][g][rr] = p;
          lsum[g] += p;
        }
    // ---- pack P^T rows: lane holds P[q=c16+g*16][kv=nt*16+quad*4+rr] ----
#pragma unroll
    for (int nt = 0; nt < 2; nt++)
#pragma unroll
      for (int g = 0; g < 2; g++) {
        ushort4 pk = make_ushort4(f2bf(sacc[nt][g][0]), f2bf(sacc[nt][g][1]),
                                  f2bf(sacc[nt][g][2]), f2bf(sacc[nt][g][3]));
        *(ushort4*)&Pl[w][g * 16 + c16][nt * 16 + quad * 4] = pk;
      }
    // ---- O^T += V^T P^T (wave-private LDS, DS in-order; no barrier) ----
    __builtin_amdgcn_s_setprio(1);
#pragma unroll
    for (int nt = 0; nt < 4; nt++) {
      bf16x8 vf = *(const bf16x8*)(kl + 2048 + (nt * 16 + c16) * 32 +
                                   ((quad ^ (c16 & 3)) << 3));
#pragma unroll
      for (int g = 0; g < 2; g++) {
        bf16x8 pf = *(const bf16x8*)&Pl[w][g * 16 + c16][quad * 8];
        oacc[g][nt] = __builtin_amdgcn_mfma_f32_16x16x32_bf16(vf, pf, oacc[g][nt], 0, 0, 0);
      }
    }
    __builtin_amdgcn_s_setprio(0);
    bfv ^= 1;
  }
#undef STAGEKV

  // ---- l: sum the 4 lanes sharing c16 (quads) ----
#pragma unroll
  for (int g = 0; g < 2; g++) {
    lsum[g] += __shfl_xor(lsum[g], 16);
    lsum[g] += __shfl_xor(lsum[g], 32);
  }

  // ---- all waves done with kvs; overlay Os on it, combine kv-split ----
  __syncthreads();
  float* osp = (float*)&kvs[0][0][0];        // Os[8][64][33] = 67.6 KB
#pragma unroll
  for (int g = 0; g < 2; g++)
#pragma unroll
    for (int nt = 0; nt < 4; nt++)
#pragma unroll
      for (int rr = 0; rr < 4; rr++)
        osp[((size_t)w * 64 + nt * 16 + quad * 4 + rr) * 33 + g * 16 + c16] = oacc[g][nt][rr];
  if (quad == 0) { Ls[w][c16] = lsum[0]; Ls[w][16 + c16] = lsum[1]; }
  __syncthreads();

#pragma unroll
  for (int e = tid; e < 2048; e += 512) {
    const int qq = e >> 6, d = e & 63;
    float s = 0.0f, l = 0.0f;
#pragma unroll
    for (int ww = 0; ww < 8; ww++) { s += osp[((size_t)ww * 64 + d) * 33 + qq]; l += Ls[ww][qq]; }
    y[(size_t)(b * 2048 + q0 + qq) * 64 + d] = s / l;
  }
}

// ---------------------------------------------------------------------------
extern "C" void kernel_launch(void* const* d_in, const int* in_sizes, int n_in,
                              void* d_out, int out_size, void* d_ws, size_t ws_size,
                              hipStream_t stream) {
  (void)in_sizes; (void)n_in; (void)out_size; (void)ws_size;
  const float* q  = (const float*)d_in[0];
  const float* k  = (const float*)d_in[1];
  const float* v  = (const float*)d_in[2];
  const float* m  = (const float*)d_in[3];
  const float* Wq = (const float*)d_in[4];
  const float* Wk = (const float*)d_in[5];
  const float* Wv = (const float*)d_in[6];
  float* y = (float*)d_out;

  u16* qh  = (u16*)d_ws;          // [4][2048][64] bf16  (1 MB)
  u16* kh  = qh + 524288;         // [4][2048][64] bf16  (1 MB)
  u16* vhT = kh + 524288;         // [4][64][2048] bf16  (1 MB)
  u16* Wbf = vhT + 524288;        // [3][64][1024] bf16  (384 KB)

  wcvt_kernel<<<dim3(192), 256, 0, stream>>>(Wq, Wk, Wv, Wbf);
  proj_kernel<<<dim3(1536), 256, 0, stream>>>(q, k, v, Wbf, qh, kh, vhT);
  attn_kernel<<<dim3(64, 4), 512, 0, stream>>>(qh, kh, vhT, m, y);
}